// Round 2
// baseline (302.999 us; speedup 1.0000x reference)
//
#include <hip/hip_runtime.h>
#include <hip/hip_bf16.h>

#define B_ 16
#define N_ 2000
#define E_ 8000
#define P_ 16000
#define XROW (E_ + N_)   // 10000 rows per batch in x
#define OROW (P_ + N_)   // 18000 rows per batch in out

typedef __hip_bfloat16 bf16;

__device__ __forceinline__ float b2f(bf16 v) { return __bfloat162float(v); }

// dtype-agnostic input load: f32 flag chooses float32 vs bf16 interpretation
__device__ __forceinline__ float ldin(const void* p, int i, int f32) {
  return f32 ? ((const float*)p)[i] : __bfloat162float(((const bf16*)p)[i]);
}
__device__ __forceinline__ void stout(void* p, size_t i, float v, int f32) {
  if (f32) ((float*)p)[i] = v;
  else     ((bf16*)p)[i] = __float2bfloat16(v);
}

// ---------- Kernel 0: input dtype detector ----------
// Interpret first 4096 elems of x as bf16. If x is really float32, the low
// 16-bit halves have random exponents -> many |v|>1e4 / non-finite hits.
__global__ __launch_bounds__(256) void k_detect(const void* __restrict__ x,
                                                int* __restrict__ flag) {
  __shared__ int sh[256];
  int t = threadIdx.x;
  const bf16* xb = (const bf16*)x;
  int bad = 0;
  for (int i = t; i < 4096; i += 256) {
    float v = b2f(xb[i]);
    if (!(fabsf(v) < 1e4f)) bad++;   // false for NaN too -> counted
  }
  sh[t] = bad; __syncthreads();
  for (int s = 128; s > 0; s >>= 1) { if (t < s) sh[t] += sh[t+s]; __syncthreads(); }
  if (t == 0) flag[0] = (sh[0] > 64) ? 1 : 0;
}

// ---------- Kernel A: combined weight precompute ----------
// W_comb = [W1; W2; W3] (each 64x64).
// A1 = W_node @ W1, A2 = W_edge @ W2, A3 = W_node @ W3
// c1 = b_node @ W1,  c3 = b_node @ W3
__global__ __launch_bounds__(256) void k_precompute(
    const void* __restrict__ W_edge, const void* __restrict__ W_node,
    const void* __restrict__ b_node, const void* __restrict__ W_comb,
    const int* __restrict__ flagp,
    float* __restrict__ A1, float* __restrict__ A2, float* __restrict__ A3,
    float* __restrict__ c1, float* __restrict__ c3) {
  const int f32 = *flagp;
  int o = blockIdx.x * 256 + threadIdx.x;
  if (o < 4096) {
    int i = o >> 6, j = o & 63;
    float a = 0.f;
    for (int k = 0; k < 64; ++k) a += ldin(W_node, i*64+k, f32) * ldin(W_comb, k*64+j, f32);
    A1[o] = a;
  } else if (o < 8192) {
    int oo = o - 4096; int i = oo >> 6, j = oo & 63;
    float a = 0.f;
    for (int k = 0; k < 64; ++k) a += ldin(W_edge, i*64+k, f32) * ldin(W_comb, (64+k)*64+j, f32);
    A2[oo] = a;
  } else if (o < 12288) {
    int oo = o - 8192; int i = oo >> 6, j = oo & 63;
    float a = 0.f;
    for (int k = 0; k < 64; ++k) a += ldin(W_node, i*64+k, f32) * ldin(W_comb, (128+k)*64+j, f32);
    A3[oo] = a;
  } else if (o < 12352) {
    int j = o - 12288;
    float a = 0.f;
    for (int k = 0; k < 64; ++k) a += ldin(b_node, k, f32) * ldin(W_comb, k*64+j, f32);
    c1[j] = a;
  } else if (o < 12416) {
    int j = o - 12352;
    float a = 0.f;
    for (int k = 0; k < 64; ++k) a += ldin(b_node, k, f32) * ldin(W_comb, (128+k)*64+j, f32);
    c3[j] = a;
  }
}

// ---------- Kernel B: node transform ----------
// per node row (B*N = 32000): h = x@W_node + b_node ; hs = x@A1 + c1 ; hd = x@A3 + c3
__global__ __launch_bounds__(256) void k_node(
    const void* __restrict__ x, const void* __restrict__ W_node,
    const void* __restrict__ b_node, const int* __restrict__ flagp,
    const float* __restrict__ A1, const float* __restrict__ A3,
    const float* __restrict__ c1, const float* __restrict__ c3,
    bf16* __restrict__ h, bf16* __restrict__ hs, bf16* __restrict__ hd) {
  __shared__ float xs[32][64];
  __shared__ float Wl[64][192];
  const int f32 = *flagp;
  int t = threadIdx.x;
  int row0 = blockIdx.x * 32;
  for (int i = t; i < 4096; i += 256) {
    int k = i >> 6, j = i & 63;
    Wl[k][j]      = ldin(W_node, i, f32);
    Wl[k][64+j]   = A1[i];
    Wl[k][128+j]  = A3[i];
  }
  for (int i = t; i < 2048; i += 256) {
    int r = i >> 6, k = i & 63;
    int row = row0 + r;
    int b = row / N_, n = row - b * N_;
    xs[r][k] = ldin(x, (b * XROW + E_ + n) * 64 + k, f32);
  }
  __syncthreads();
  for (int tt = t; tt < 384; tt += 256) {
    int rt = tt / 48, ct = tt - rt * 48;
    int r0 = rt * 4, c0 = ct * 4;
    float acc[4][4] = {{0.f}};
    for (int k = 0; k < 64; ++k) {
      float4 wv = *reinterpret_cast<const float4*>(&Wl[k][c0]);
      #pragma unroll
      for (int ii = 0; ii < 4; ++ii) {
        float xv = xs[r0+ii][k];
        acc[ii][0] += xv * wv.x; acc[ii][1] += xv * wv.y;
        acc[ii][2] += xv * wv.z; acc[ii][3] += xv * wv.w;
      }
    }
    #pragma unroll
    for (int ii = 0; ii < 4; ++ii) {
      int row = row0 + r0 + ii;
      #pragma unroll
      for (int jj = 0; jj < 4; ++jj) {
        int c = c0 + jj;
        float bias; bf16* dstp;
        if (c < 64)       { bias = ldin(b_node, c, f32); dstp = h  + row*64 + c; }
        else if (c < 128) { bias = c1[c-64];             dstp = hs + row*64 + (c-64); }
        else              { bias = c3[c-128];            dstp = hd + row*64 + (c-128); }
        *dstp = __float2bfloat16(acc[ii][jj] + bias);
      }
    }
  }
}

// ---------- Kernel C: edge transform ----------
__global__ __launch_bounds__(256) void k_edge(
    const void* __restrict__ x, const int* __restrict__ flagp,
    const float* __restrict__ A2, bf16* __restrict__ fe) {
  __shared__ float xs[64][64];
  __shared__ float Wl[64][64];
  const int f32 = *flagp;
  int t = threadIdx.x;
  int row0 = blockIdx.x * 64;
  for (int i = t; i < 4096; i += 256) Wl[i >> 6][i & 63] = A2[i];
  for (int i = t; i < 4096; i += 256) {
    int r = i >> 6, k = i & 63;
    int row = row0 + r;
    int b = row / E_, e = row - b * E_;
    xs[r][k] = ldin(x, (b * XROW + e) * 64 + k, f32);
  }
  __syncthreads();
  int rt = t >> 4, ct = t & 15;
  int r0 = rt * 4, c0 = ct * 4;
  float acc[4][4] = {{0.f}};
  for (int k = 0; k < 64; ++k) {
    float4 wv = *reinterpret_cast<const float4*>(&Wl[k][c0]);
    #pragma unroll
    for (int ii = 0; ii < 4; ++ii) {
      float xv = xs[r0+ii][k];
      acc[ii][0] += xv * wv.x; acc[ii][1] += xv * wv.y;
      acc[ii][2] += xv * wv.z; acc[ii][3] += xv * wv.w;
    }
  }
  #pragma unroll
  for (int ii = 0; ii < 4; ++ii) {
    int row = row0 + r0 + ii;
    #pragma unroll
    for (int jj = 0; jj < 4; ++jj)
      fe[row*64 + c0 + jj] = __float2bfloat16(acc[ii][jj]);
  }
}

// ---------- Kernel D: gather + combine + leaky_relu + attention logit ----------
__global__ __launch_bounds__(256) void k_combine(
    const bf16* __restrict__ hs, const bf16* __restrict__ hd,
    const bf16* __restrict__ fe, const void* __restrict__ b_comb,
    const void* __restrict__ w_attn, const int* __restrict__ flagp,
    const int* __restrict__ src, const int* __restrict__ dst,
    const int* __restrict__ eidx,
    void* __restrict__ out, float* __restrict__ logits) {
  const int f32 = *flagp;
  int t = threadIdx.x;
  int lane = t & 63;
  int r = blockIdx.x * 4 + (t >> 6);      // [0, B*P)
  int b = r / P_, p = r - b * P_;
  int s = src[p], d2 = dst[p], e = eidx[p];
  float v = b2f(hs[(b*N_ + s)*64 + lane])
          + b2f(fe[(b*E_ + e)*64 + lane])
          + b2f(hd[(b*N_ + d2)*64 + lane])
          + ldin(b_comb, lane, f32);
  v = v > 0.f ? v : 0.01f * v;
  stout(out, (size_t)(b*OROW + p)*64 + lane, v, f32);
  float l = v * ldin(w_attn, lane, f32);
  #pragma unroll
  for (int o = 32; o > 0; o >>= 1) l += __shfl_down(l, o, 64);
  if (lane == 0) logits[b*P_ + p] = l;
}

// ---------- Kernel E: per-batch softmax stats ----------
__global__ __launch_bounds__(256) void k_softmax(
    const float* __restrict__ logits, float* __restrict__ mb, float* __restrict__ sb) {
  __shared__ float red[256];
  int b = blockIdx.x, t = threadIdx.x;
  float m = -1e30f;
  for (int p = t; p < P_; p += 256) m = fmaxf(m, logits[b*P_ + p]);
  red[t] = m; __syncthreads();
  for (int s = 128; s > 0; s >>= 1) { if (t < s) red[t] = fmaxf(red[t], red[t+s]); __syncthreads(); }
  float M = red[0]; __syncthreads();
  float sum = 0.f;
  for (int p = t; p < P_; p += 256) sum += __expf(logits[b*P_ + p] - M);
  red[t] = sum; __syncthreads();
  for (int s = 128; s > 0; s >>= 1) { if (t < s) red[t] += red[t+s]; __syncthreads(); }
  if (t == 0) { mb[b] = M; sb[b] = 1.0f / red[0]; }
}

// ---------- Kernel F: h_out accumulation (src sorted; binary-search range) ----------
__global__ __launch_bounds__(64) void k_hout(
    const bf16* __restrict__ h, const float* __restrict__ logits,
    const float* __restrict__ mb, const float* __restrict__ sb,
    const int* __restrict__ src, const int* __restrict__ dst,
    const int* __restrict__ flagp, void* __restrict__ out) {
  const int f32 = *flagp;
  int n = blockIdx.x, b = blockIdx.y;
  int d = threadIdx.x;
  int lo = 0, hi = P_;
  while (lo < hi) { int mid = (lo + hi) >> 1; if (src[mid] < n) lo = mid + 1; else hi = mid; }
  int start = lo;
  hi = P_;
  while (lo < hi) { int mid = (lo + hi) >> 1; if (src[mid] <= n) lo = mid + 1; else hi = mid; }
  int end = lo;
  float M = mb[b], inv = sb[b];
  float acc = 0.f;
  for (int p = start; p < end; ++p) {
    float a = __expf(logits[b*P_ + p] - M) * inv;
    acc += a * b2f(h[(b*N_ + dst[p])*64 + d]);
  }
  stout(out, (size_t)(b*OROW + P_ + n)*64 + d, acc, f32);
}

extern "C" void kernel_launch(void* const* d_in, const int* in_sizes, int n_in,
                              void* d_out, int out_size, void* d_ws, size_t ws_size,
                              hipStream_t stream) {
  const void* x      = d_in[0];
  const void* W_edge = d_in[1];
  const void* W_node = d_in[2];
  const void* b_node = d_in[3];
  const void* W_comb = d_in[4];
  const void* b_comb = d_in[5];
  const void* w_attn = d_in[6];
  const int* src  = (const int*)d_in[7];
  const int* dst  = (const int*)d_in[8];
  const int* eidx = (const int*)d_in[9];

  // workspace layout
  int*   flag = (int*)d_ws;              // 16 floats reserved
  float* A1 = (float*)d_ws + 16;         // 4096
  float* A2 = A1 + 4096;                 // 4096
  float* A3 = A2 + 4096;                 // 4096
  float* c1 = A3 + 4096;                 // 64
  float* c3 = c1 + 64;                   // 64
  float* logits = c3 + 64;               // B*P = 256000
  float* mb = logits + B_*P_;            // 16
  float* sb = mb + B_;                   // 16
  bf16* h  = (bf16*)(sb + B_);           // B*N*64
  bf16* hs = h  + B_*N_*64;
  bf16* hd = hs + B_*N_*64;
  bf16* fe = hd + B_*N_*64;              // B*E*64

  k_detect<<<1, 256, 0, stream>>>(x, flag);
  k_precompute<<<49, 256, 0, stream>>>(W_edge, W_node, b_node, W_comb, flag, A1, A2, A3, c1, c3);
  k_node<<<(B_*N_)/32, 256, 0, stream>>>(x, W_node, b_node, flag, A1, A3, c1, c3, h, hs, hd);
  k_edge<<<(B_*E_)/64, 256, 0, stream>>>(x, flag, A2, fe);
  k_combine<<<(B_*P_)/4, 256, 0, stream>>>(hs, hd, fe, b_comb, w_attn, flag, src, dst, eidx, d_out, logits);
  k_softmax<<<B_, 256, 0, stream>>>(logits, mb, sb);
  k_hout<<<dim3(N_, B_), 64, 0, stream>>>(h, logits, mb, sb, src, dst, flag, d_out);
}

// Round 3
// 252.728 us; speedup vs baseline: 1.1989x; 1.1989x over previous
//
#include <hip/hip_runtime.h>
#include <hip/hip_bf16.h>

#define B_ 16
#define N_ 2000
#define E_ 8000
#define P_ 16000
#define XROW (E_ + N_)   // 10000 rows per batch in x
#define OROW (P_ + N_)   // 18000 rows per batch in out

typedef __hip_bfloat16 bf16;
typedef unsigned short u16;
typedef unsigned int u32;

__device__ __forceinline__ float b2f(bf16 v) { return __bfloat162float(v); }
__device__ __forceinline__ float u2f(u16 u) { return __uint_as_float(((u32)u) << 16); }
__device__ __forceinline__ u16 f2bu(float v) {
  bf16 b = __float2bfloat16(v);
  return *reinterpret_cast<u16*>(&b);
}

// dtype-agnostic input load: f32 flag chooses float32 vs bf16 interpretation
__device__ __forceinline__ float ldin(const void* p, int i, int f32) {
  return f32 ? ((const float*)p)[i] : __bfloat162float(((const bf16*)p)[i]);
}
__device__ __forceinline__ void stout(void* p, size_t i, float v, int f32) {
  if (f32) ((float*)p)[i] = v;
  else     ((bf16*)p)[i] = __float2bfloat16(v);
}

// ---------- Kernel 0: input dtype detector ----------
__global__ __launch_bounds__(256) void k_detect(const void* __restrict__ x,
                                                int* __restrict__ flag) {
  __shared__ int sh[256];
  int t = threadIdx.x;
  const bf16* xb = (const bf16*)x;
  int bad = 0;
  for (int i = t; i < 4096; i += 256) {
    float v = b2f(xb[i]);
    if (!(fabsf(v) < 1e4f)) bad++;
  }
  sh[t] = bad; __syncthreads();
  for (int s = 128; s > 0; s >>= 1) { if (t < s) sh[t] += sh[t+s]; __syncthreads(); }
  if (t == 0) flag[0] = (sh[0] > 64) ? 1 : 0;
}

// ---------- Kernel A: combined weight precompute ----------
__global__ __launch_bounds__(256) void k_precompute(
    const void* __restrict__ W_edge, const void* __restrict__ W_node,
    const void* __restrict__ b_node, const void* __restrict__ W_comb,
    const int* __restrict__ flagp,
    float* __restrict__ A1, float* __restrict__ A2, float* __restrict__ A3,
    float* __restrict__ c1, float* __restrict__ c3) {
  const int f32 = *flagp;
  int o = blockIdx.x * 256 + threadIdx.x;
  if (o < 4096) {
    int i = o >> 6, j = o & 63;
    float a = 0.f;
    for (int k = 0; k < 64; ++k) a += ldin(W_node, i*64+k, f32) * ldin(W_comb, k*64+j, f32);
    A1[o] = a;
  } else if (o < 8192) {
    int oo = o - 4096; int i = oo >> 6, j = oo & 63;
    float a = 0.f;
    for (int k = 0; k < 64; ++k) a += ldin(W_edge, i*64+k, f32) * ldin(W_comb, (64+k)*64+j, f32);
    A2[oo] = a;
  } else if (o < 12288) {
    int oo = o - 8192; int i = oo >> 6, j = oo & 63;
    float a = 0.f;
    for (int k = 0; k < 64; ++k) a += ldin(W_node, i*64+k, f32) * ldin(W_comb, (128+k)*64+j, f32);
    A3[oo] = a;
  } else if (o < 12352) {
    int j = o - 12288;
    float a = 0.f;
    for (int k = 0; k < 64; ++k) a += ldin(b_node, k, f32) * ldin(W_comb, k*64+j, f32);
    c1[j] = a;
  } else if (o < 12416) {
    int j = o - 12352;
    float a = 0.f;
    for (int k = 0; k < 64; ++k) a += ldin(b_node, k, f32) * ldin(W_comb, (128+k)*64+j, f32);
    c3[j] = a;
  }
}

// ---------- staging helper: 4 consecutive input elems -> 4 floats ----------
__device__ __forceinline__ void ld4(const void* p, size_t i, int f32, float* o) {
  if (f32) {
    float4 v = *reinterpret_cast<const float4*>((const float*)p + i);
    o[0] = v.x; o[1] = v.y; o[2] = v.z; o[3] = v.w;
  } else {
    ushort4 v = *reinterpret_cast<const ushort4*>((const u16*)p + i);
    o[0] = u2f(v.x); o[1] = u2f(v.y); o[2] = u2f(v.z); o[3] = u2f(v.w);
  }
}

// ---------- Kernel B: node transform ----------
// per node row (B*N = 32000): h = x@W_node + b_node ; hs = x@A1 + c1 ; hd = x@A3 + c3
__global__ __launch_bounds__(256) void k_node(
    const void* __restrict__ x, const void* __restrict__ W_node,
    const void* __restrict__ b_node, const int* __restrict__ flagp,
    const float* __restrict__ A1, const float* __restrict__ A3,
    const float* __restrict__ c1, const float* __restrict__ c3,
    bf16* __restrict__ h, bf16* __restrict__ hs, bf16* __restrict__ hd) {
  __shared__ float xs[32][64];
  __shared__ float Wl[64][192];
  const int f32 = *flagp;
  int t = threadIdx.x;
  int row0 = blockIdx.x * 32;
  for (int i = t*4; i < 4096; i += 1024) {
    int k = i >> 6, j = i & 63;
    ld4(W_node, i, f32, &Wl[k][j]);
    *reinterpret_cast<float4*>(&Wl[k][64+j])  = *reinterpret_cast<const float4*>(A1 + i);
    *reinterpret_cast<float4*>(&Wl[k][128+j]) = *reinterpret_cast<const float4*>(A3 + i);
  }
  for (int i = t*4; i < 2048; i += 1024) {
    int r = i >> 6, k = i & 63;
    int row = row0 + r;
    int b = row / N_, n = row - b * N_;
    ld4(x, (size_t)(b * XROW + E_ + n) * 64 + k, f32, &xs[r][k]);
  }
  __syncthreads();
  for (int tt = t; tt < 384; tt += 256) {
    int rt = tt / 48, ct = tt - rt * 48;
    int r0 = rt * 4, c0 = ct * 4;
    float acc[4][4] = {{0.f}};
    for (int k = 0; k < 64; ++k) {
      float4 wv = *reinterpret_cast<const float4*>(&Wl[k][c0]);
      #pragma unroll
      for (int ii = 0; ii < 4; ++ii) {
        float xv = xs[r0+ii][k];
        acc[ii][0] += xv * wv.x; acc[ii][1] += xv * wv.y;
        acc[ii][2] += xv * wv.z; acc[ii][3] += xv * wv.w;
      }
    }
    #pragma unroll
    for (int ii = 0; ii < 4; ++ii) {
      int row = row0 + r0 + ii;
      #pragma unroll
      for (int jj = 0; jj < 4; ++jj) {
        int c = c0 + jj;
        float bias; bf16* dstp;
        if (c < 64)       { bias = ldin(b_node, c, f32); dstp = h  + row*64 + c; }
        else if (c < 128) { bias = c1[c-64];             dstp = hs + row*64 + (c-64); }
        else              { bias = c3[c-128];            dstp = hd + row*64 + (c-128); }
        *dstp = __float2bfloat16(acc[ii][jj] + bias);
      }
    }
  }
}

// ---------- Kernel C: edge transform: fe = x_edge @ A2 ----------
__global__ __launch_bounds__(256) void k_edge(
    const void* __restrict__ x, const int* __restrict__ flagp,
    const float* __restrict__ A2, bf16* __restrict__ fe) {
  __shared__ float xs[64][64];
  __shared__ float Wl[64][64];
  const int f32 = *flagp;
  int t = threadIdx.x;
  int row0 = blockIdx.x * 64;
  for (int i = t*4; i < 4096; i += 1024) {
    *reinterpret_cast<float4*>(&Wl[i >> 6][i & 63]) = *reinterpret_cast<const float4*>(A2 + i);
    int r = i >> 6, k = i & 63;
    int row = row0 + r;
    int b = row / E_, e = row - b * E_;
    ld4(x, (size_t)(b * XROW + e) * 64 + k, f32, &xs[r][k]);
  }
  __syncthreads();
  int rt = t >> 4, ct = t & 15;
  int r0 = rt * 4, c0 = ct * 4;
  float acc[4][4] = {{0.f}};
  for (int k = 0; k < 64; ++k) {
    float4 wv = *reinterpret_cast<const float4*>(&Wl[k][c0]);
    #pragma unroll
    for (int ii = 0; ii < 4; ++ii) {
      float xv = xs[r0+ii][k];
      acc[ii][0] += xv * wv.x; acc[ii][1] += xv * wv.y;
      acc[ii][2] += xv * wv.z; acc[ii][3] += xv * wv.w;
    }
  }
  #pragma unroll
  for (int ii = 0; ii < 4; ++ii) {
    int row = row0 + r0 + ii;
    ushort4 o;
    o.x = f2bu(acc[ii][0]); o.y = f2bu(acc[ii][1]);
    o.z = f2bu(acc[ii][2]); o.w = f2bu(acc[ii][3]);
    *reinterpret_cast<ushort4*>((u16*)fe + (size_t)row*64 + c0) = o;
  }
}

// ---------- Kernel D: gather + combine + leaky_relu + attention logit ----------
// 16 lanes per row, 4 channels/lane (ushort4 gathers). Block = 16 rows.
__global__ __launch_bounds__(256) void k_combine(
    const bf16* __restrict__ hs, const bf16* __restrict__ hd,
    const bf16* __restrict__ fe, const void* __restrict__ b_comb,
    const void* __restrict__ w_attn, const int* __restrict__ flagp,
    const int* __restrict__ src, const int* __restrict__ dst,
    const int* __restrict__ eidx,
    void* __restrict__ out, float* __restrict__ logits) {
  const int f32 = *flagp;
  int t = threadIdx.x;
  int lane = t & 63;
  int grp = lane >> 4;     // row within wave
  int sub = lane & 15;     // channel group
  int c0 = sub * 4;
  int r = blockIdx.x * 16 + (t >> 6) * 4 + grp;   // [0, B*P)
  int b = r / P_, p = r - b * P_;
  int s = src[p], d2 = dst[p], e = eidx[p];
  ushort4 a4 = *reinterpret_cast<const ushort4*>((const u16*)hs + (size_t)(b*N_ + s)*64 + c0);
  ushort4 f4 = *reinterpret_cast<const ushort4*>((const u16*)fe + (size_t)(b*E_ + e)*64 + c0);
  ushort4 d4 = *reinterpret_cast<const ushort4*>((const u16*)hd + (size_t)(b*N_ + d2)*64 + c0);
  const u16* ap = (const u16*)&a4;
  const u16* fp = (const u16*)&f4;
  const u16* dp = (const u16*)&d4;
  float v[4]; float l = 0.f;
  #pragma unroll
  for (int j = 0; j < 4; ++j) {
    float vv = u2f(ap[j]) + u2f(fp[j]) + u2f(dp[j]) + ldin(b_comb, c0 + j, f32);
    vv = vv > 0.f ? vv : 0.01f * vv;
    v[j] = vv;
    l += vv * ldin(w_attn, c0 + j, f32);
  }
  size_t obase = (size_t)(b*OROW + p)*64 + c0;
  if (f32) {
    float4 o4; o4.x = v[0]; o4.y = v[1]; o4.z = v[2]; o4.w = v[3];
    *reinterpret_cast<float4*>((float*)out + obase) = o4;
  } else {
    ushort4 o4;
    o4.x = f2bu(v[0]); o4.y = f2bu(v[1]); o4.z = f2bu(v[2]); o4.w = f2bu(v[3]);
    *reinterpret_cast<ushort4*>((u16*)out + obase) = o4;
  }
  #pragma unroll
  for (int o = 8; o > 0; o >>= 1) l += __shfl_down(l, o, 16);
  if (sub == 0) logits[b*P_ + p] = l;
}

// ---------- Kernel E1: partial softmax stats (online) ----------
// grid (B_, 32): each block covers 500 logits; writes partial (max, sum).
__global__ __launch_bounds__(256) void k_softmax1(
    const float* __restrict__ logits,
    float* __restrict__ mpart, float* __restrict__ spart) {
  __shared__ float red[256];
  int b = blockIdx.x, chunk = blockIdx.y, t = threadIdx.x;
  int p0 = chunk * 500;
  float l0 = (t < 500)       ? logits[b*P_ + p0 + t]       : -1e30f;
  float l1 = (t + 256 < 500) ? logits[b*P_ + p0 + t + 256] : -1e30f;
  float m = fmaxf(l0, l1);
  red[t] = m; __syncthreads();
  for (int s = 128; s > 0; s >>= 1) { if (t < s) red[t] = fmaxf(red[t], red[t+s]); __syncthreads(); }
  float M = red[0]; __syncthreads();
  float s = __expf(l0 - M) + __expf(l1 - M);
  red[t] = s; __syncthreads();
  for (int ss = 128; ss > 0; ss >>= 1) { if (t < ss) red[t] += red[t+ss]; __syncthreads(); }
  if (t == 0) { mpart[b*32 + chunk] = M; spart[b*32 + chunk] = red[0]; }
}

// ---------- Kernel E2: merge partials -> per-batch (max, 1/sum) ----------
__global__ __launch_bounds__(64) void k_softmax2(
    const float* __restrict__ mpart, const float* __restrict__ spart,
    float* __restrict__ mb, float* __restrict__ sb) {
  int t = threadIdx.x;
  if (t < B_) {
    float M = -1e30f;
    for (int j = 0; j < 32; ++j) M = fmaxf(M, mpart[t*32 + j]);
    float S = 0.f;
    for (int j = 0; j < 32; ++j) S += spart[t*32 + j] * __expf(mpart[t*32 + j] - M);
    mb[t] = M; sb[t] = 1.0f / S;
  }
}

// ---------- Kernel F: h_out accumulation (src sorted; binary-search range) ----------
// grid (N_, B_/4), block 256: wave w handles batch blockIdx.y*4+w, node blockIdx.x.
__global__ __launch_bounds__(256) void k_hout(
    const bf16* __restrict__ h, const float* __restrict__ logits,
    const float* __restrict__ mb, const float* __restrict__ sb,
    const int* __restrict__ src, const int* __restrict__ dst,
    const int* __restrict__ flagp, void* __restrict__ out) {
  const int f32 = *flagp;
  int n = blockIdx.x;
  int t = threadIdx.x;
  int b = blockIdx.y * 4 + (t >> 6);
  int d = t & 63;
  int lo = 0, hi = P_;
  while (lo < hi) { int mid = (lo + hi) >> 1; if (src[mid] < n) lo = mid + 1; else hi = mid; }
  int start = lo;
  hi = P_;
  while (lo < hi) { int mid = (lo + hi) >> 1; if (src[mid] <= n) lo = mid + 1; else hi = mid; }
  int end = lo;
  float M = mb[b], inv = sb[b];
  float acc = 0.f;
  for (int p = start; p < end; ++p) {
    float a = __expf(logits[b*P_ + p] - M) * inv;
    acc += a * b2f(h[(b*N_ + dst[p])*64 + d]);
  }
  stout(out, (size_t)(b*OROW + P_ + n)*64 + d, acc, f32);
}

extern "C" void kernel_launch(void* const* d_in, const int* in_sizes, int n_in,
                              void* d_out, int out_size, void* d_ws, size_t ws_size,
                              hipStream_t stream) {
  const void* x      = d_in[0];
  const void* W_edge = d_in[1];
  const void* W_node = d_in[2];
  const void* b_node = d_in[3];
  const void* W_comb = d_in[4];
  const void* b_comb = d_in[5];
  const void* w_attn = d_in[6];
  const int* src  = (const int*)d_in[7];
  const int* dst  = (const int*)d_in[8];
  const int* eidx = (const int*)d_in[9];

  // workspace layout
  int*   flag = (int*)d_ws;              // 16 floats reserved
  float* A1 = (float*)d_ws + 16;         // 4096
  float* A2 = A1 + 4096;                 // 4096
  float* A3 = A2 + 4096;                 // 4096
  float* c1 = A3 + 4096;                 // 64
  float* c3 = c1 + 64;                   // 64
  float* logits = c3 + 64;               // B*P = 256000
  float* mb = logits + B_*P_;            // 16
  float* sb = mb + B_;                   // 16
  float* mpart = sb + B_;                // 512
  float* spart = mpart + 512;            // 512
  bf16* h  = (bf16*)(spart + 512);       // B*N*64
  bf16* hs = h  + B_*N_*64;
  bf16* hd = hs + B_*N_*64;
  bf16* fe = hd + B_*N_*64;              // B*E*64

  k_detect<<<1, 256, 0, stream>>>(x, flag);
  k_precompute<<<49, 256, 0, stream>>>(W_edge, W_node, b_node, W_comb, flag, A1, A2, A3, c1, c3);
  k_node<<<(B_*N_)/32, 256, 0, stream>>>(x, W_node, b_node, flag, A1, A3, c1, c3, h, hs, hd);
  k_edge<<<(B_*E_)/64, 256, 0, stream>>>(x, flag, A2, fe);
  k_combine<<<(B_*P_)/16, 256, 0, stream>>>(hs, hd, fe, b_comb, w_attn, flag, src, dst, eidx, d_out, logits);
  k_softmax1<<<dim3(B_, 32), 256, 0, stream>>>(logits, mpart, spart);
  k_softmax2<<<1, 64, 0, stream>>>(mpart, spart, mb, sb);
  k_hout<<<dim3(N_, B_/4), 256, 0, stream>>>(h, logits, mb, sb, src, dst, flag, d_out);
}

// Round 4
// 221.912 us; speedup vs baseline: 1.3654x; 1.1389x over previous
//
#include <hip/hip_runtime.h>
#include <hip/hip_bf16.h>

#define B_ 16
#define N_ 2000
#define E_ 8000
#define P_ 16000
#define XROW (E_ + N_)   // 10000 rows per batch in x
#define OROW (P_ + N_)   // 18000 rows per batch in out

typedef __hip_bfloat16 bf16;
typedef unsigned short u16;
typedef unsigned int u32;

__device__ __forceinline__ float b2f(bf16 v) { return __bfloat162float(v); }
__device__ __forceinline__ float u2f(u16 u) { return __uint_as_float(((u32)u) << 16); }
__device__ __forceinline__ float lo2f(u32 u) { return __uint_as_float(u << 16); }
__device__ __forceinline__ float hi2f(u32 u) { return __uint_as_float(u & 0xFFFF0000u); }
__device__ __forceinline__ u16 f2bu(float v) {
  bf16 b = __float2bfloat16(v);
  return *reinterpret_cast<u16*>(&b);
}

// dtype-agnostic input load
__device__ __forceinline__ float ldin(const void* p, int i, int f32) {
  return f32 ? ((const float*)p)[i] : __bfloat162float(((const bf16*)p)[i]);
}

// per-block dtype self-detect: view first 512B of x as bf16; f32 data's low
// halves have random exponents -> ~70% of lanes see |v|>1e4 or NaN.
__device__ __forceinline__ int detect_f32(const void* x) {
  int lane = threadIdx.x & 63;
  ushort4 v = reinterpret_cast<const ushort4*>(x)[lane];
  int bad = 0;
  float f0 = u2f(v.x), f1 = u2f(v.y), f2 = u2f(v.z), f3 = u2f(v.w);
  if (!(fabsf(f0) < 1e4f)) bad++;
  if (!(fabsf(f1) < 1e4f)) bad++;
  if (!(fabsf(f2) < 1e4f)) bad++;
  if (!(fabsf(f3) < 1e4f)) bad++;
  unsigned long long m = __ballot(bad > 0);
  return __popcll(m) > 8;
}

// ---------- staging helper: 4 consecutive input elems -> 4 floats ----------
__device__ __forceinline__ void ld4(const void* p, size_t i, int f32, float* o) {
  if (f32) {
    float4 v = *reinterpret_cast<const float4*>((const float*)p + i);
    o[0] = v.x; o[1] = v.y; o[2] = v.z; o[3] = v.w;
  } else {
    ushort4 v = *reinterpret_cast<const ushort4*>((const u16*)p + i);
    o[0] = u2f(v.x); o[1] = u2f(v.y); o[2] = u2f(v.z); o[3] = u2f(v.w);
  }
}

// ---------- Kernel A: combined weight precompute ----------
// W_comb = [W1; W2; W3]. A1 = W_node@W1, A2 = W_edge@W2, A3 = W_node@W3,
// c1 = b_node@W1, c3 = b_node@W3
__global__ __launch_bounds__(256) void k_pre(
    const void* __restrict__ x,
    const void* __restrict__ W_edge, const void* __restrict__ W_node,
    const void* __restrict__ b_node, const void* __restrict__ W_comb,
    float* __restrict__ A1, float* __restrict__ A2, float* __restrict__ A3,
    float* __restrict__ c1, float* __restrict__ c3) {
  const int f32 = detect_f32(x);
  int o = blockIdx.x * 256 + threadIdx.x;
  if (o < 4096) {
    int i = o >> 6, j = o & 63;
    float a = 0.f;
    for (int k = 0; k < 64; ++k) a += ldin(W_node, i*64+k, f32) * ldin(W_comb, k*64+j, f32);
    A1[o] = a;
  } else if (o < 8192) {
    int oo = o - 4096; int i = oo >> 6, j = oo & 63;
    float a = 0.f;
    for (int k = 0; k < 64; ++k) a += ldin(W_edge, i*64+k, f32) * ldin(W_comb, (64+k)*64+j, f32);
    A2[oo] = a;
  } else if (o < 12288) {
    int oo = o - 8192; int i = oo >> 6, j = oo & 63;
    float a = 0.f;
    for (int k = 0; k < 64; ++k) a += ldin(W_node, i*64+k, f32) * ldin(W_comb, (128+k)*64+j, f32);
    A3[oo] = a;
  } else if (o < 12352) {
    int j = o - 12288;
    float a = 0.f;
    for (int k = 0; k < 64; ++k) a += ldin(b_node, k, f32) * ldin(W_comb, k*64+j, f32);
    c1[j] = a;
  } else if (o < 12416) {
    int j = o - 12352;
    float a = 0.f;
    for (int k = 0; k < 64; ++k) a += ldin(b_node, k, f32) * ldin(W_comb, (128+k)*64+j, f32);
    c3[j] = a;
  }
}

// ---------- Kernel B: fused node+edge transform ----------
// blocks [0,1000): node rows, 32/block: h = x@W_node+b_node; hs = x@A1+c1; hd = x@A3+c3
// blocks [1000,3000): edge rows, 64/block: fe = x@A2
__global__ __launch_bounds__(256) void k_transform(
    const void* __restrict__ x, const void* __restrict__ W_node,
    const void* __restrict__ b_node,
    const float* __restrict__ A1, const float* __restrict__ A2,
    const float* __restrict__ A3,
    const float* __restrict__ c1, const float* __restrict__ c3,
    bf16* __restrict__ h, bf16* __restrict__ hs, bf16* __restrict__ hd,
    bf16* __restrict__ fe) {
  __shared__ float smem[14336];
  const int f32 = detect_f32(x);
  int t = threadIdx.x;
  if (blockIdx.x < 1000) {
    float (*xs)[64]  = reinterpret_cast<float(*)[64]>(smem);          // 32x64
    float (*Wl)[192] = reinterpret_cast<float(*)[192]>(smem + 2048);  // 64x192
    int row0 = blockIdx.x * 32;
    for (int i = t*4; i < 4096; i += 1024) {
      int k = i >> 6, j = i & 63;
      ld4(W_node, i, f32, &Wl[k][j]);
      *reinterpret_cast<float4*>(&Wl[k][64+j])  = *reinterpret_cast<const float4*>(A1 + i);
      *reinterpret_cast<float4*>(&Wl[k][128+j]) = *reinterpret_cast<const float4*>(A3 + i);
    }
    for (int i = t*4; i < 2048; i += 1024) {
      int r = i >> 6, k = i & 63;
      int row = row0 + r;
      int b = row / N_, n = row - b * N_;
      ld4(x, (size_t)(b * XROW + E_ + n) * 64 + k, f32, &xs[r][k]);
    }
    __syncthreads();
    for (int tt = t; tt < 384; tt += 256) {
      int rt = tt / 48, ct = tt - rt * 48;
      int r0 = rt * 4, c0 = ct * 4;
      float acc[4][4] = {{0.f}};
      for (int k = 0; k < 64; ++k) {
        float4 wv = *reinterpret_cast<const float4*>(&Wl[k][c0]);
        #pragma unroll
        for (int ii = 0; ii < 4; ++ii) {
          float xv = xs[r0+ii][k];
          acc[ii][0] += xv * wv.x; acc[ii][1] += xv * wv.y;
          acc[ii][2] += xv * wv.z; acc[ii][3] += xv * wv.w;
        }
      }
      #pragma unroll
      for (int ii = 0; ii < 4; ++ii) {
        int row = row0 + r0 + ii;
        #pragma unroll
        for (int jj = 0; jj < 4; ++jj) {
          int c = c0 + jj;
          float bias; bf16* dstp;
          if (c < 64)       { bias = ldin(b_node, c, f32); dstp = h  + row*64 + c; }
          else if (c < 128) { bias = c1[c-64];             dstp = hs + row*64 + (c-64); }
          else              { bias = c3[c-128];            dstp = hd + row*64 + (c-128); }
          *dstp = __float2bfloat16(acc[ii][jj] + bias);
        }
      }
    }
  } else {
    float (*xs)[64] = reinterpret_cast<float(*)[64]>(smem);          // 64x64
    float (*Wl)[64] = reinterpret_cast<float(*)[64]>(smem + 4096);   // 64x64
    int row0 = (blockIdx.x - 1000) * 64;
    for (int i = t*4; i < 4096; i += 1024) {
      *reinterpret_cast<float4*>(&Wl[i >> 6][i & 63]) = *reinterpret_cast<const float4*>(A2 + i);
      int r = i >> 6, k = i & 63;
      int row = row0 + r;
      int b = row / E_, e = row - b * E_;
      ld4(x, (size_t)(b * XROW + e) * 64 + k, f32, &xs[r][k]);
    }
    __syncthreads();
    int rt = t >> 4, ct = t & 15;
    int r0 = rt * 4, c0 = ct * 4;
    float acc[4][4] = {{0.f}};
    for (int k = 0; k < 64; ++k) {
      float4 wv = *reinterpret_cast<const float4*>(&Wl[k][c0]);
      #pragma unroll
      for (int ii = 0; ii < 4; ++ii) {
        float xv = xs[r0+ii][k];
        acc[ii][0] += xv * wv.x; acc[ii][1] += xv * wv.y;
        acc[ii][2] += xv * wv.z; acc[ii][3] += xv * wv.w;
      }
    }
    #pragma unroll
    for (int ii = 0; ii < 4; ++ii) {
      int row = row0 + r0 + ii;
      ushort4 o;
      o.x = f2bu(acc[ii][0]); o.y = f2bu(acc[ii][1]);
      o.z = f2bu(acc[ii][2]); o.w = f2bu(acc[ii][3]);
      *reinterpret_cast<ushort4*>((u16*)fe + (size_t)row*64 + c0) = o;
    }
  }
}

// ---------- Kernel C: gather+combine+lrelu+logit + per-block softmax partial --
// 8 lanes/row x 8 ch (uint4 = 16B gathers), 32 rows/block (all same batch).
__global__ __launch_bounds__(256) void k_combine(
    const void* __restrict__ x,
    const bf16* __restrict__ hs, const bf16* __restrict__ hd,
    const bf16* __restrict__ fe, const void* __restrict__ b_comb,
    const void* __restrict__ w_attn,
    const int* __restrict__ src, const int* __restrict__ dst,
    const int* __restrict__ eidx,
    void* __restrict__ out, float* __restrict__ logits,
    float* __restrict__ mpart, float* __restrict__ spart) {
  const int f32 = detect_f32(x);
  __shared__ float bias[64], watt[64];
  __shared__ float ld_log[32];
  int t = threadIdx.x;
  if (t < 64) { bias[t] = ldin(b_comb, t, f32); watt[t] = ldin(w_attn, t, f32); }
  __syncthreads();
  int lane = t & 63, wave = t >> 6;
  int grp = lane >> 3, sub = lane & 7, c0 = sub * 8;
  int r = blockIdx.x * 32 + wave * 8 + grp;   // [0, B*P)
  int b = r / P_, p = r - b * P_;
  int s = src[p], d2 = dst[p], e = eidx[p];
  uint4 ua = *reinterpret_cast<const uint4*>((const u16*)hs + (size_t)(b*N_ + s)*64 + c0);
  uint4 uf = *reinterpret_cast<const uint4*>((const u16*)fe + (size_t)(b*E_ + e)*64 + c0);
  uint4 ud = *reinterpret_cast<const uint4*>((const u16*)hd + (size_t)(b*N_ + d2)*64 + c0);
  float v[8];
  v[0] = lo2f(ua.x) + lo2f(uf.x) + lo2f(ud.x) + bias[c0+0];
  v[1] = hi2f(ua.x) + hi2f(uf.x) + hi2f(ud.x) + bias[c0+1];
  v[2] = lo2f(ua.y) + lo2f(uf.y) + lo2f(ud.y) + bias[c0+2];
  v[3] = hi2f(ua.y) + hi2f(uf.y) + hi2f(ud.y) + bias[c0+3];
  v[4] = lo2f(ua.z) + lo2f(uf.z) + lo2f(ud.z) + bias[c0+4];
  v[5] = hi2f(ua.z) + hi2f(uf.z) + hi2f(ud.z) + bias[c0+5];
  v[6] = lo2f(ua.w) + lo2f(uf.w) + lo2f(ud.w) + bias[c0+6];
  v[7] = hi2f(ua.w) + hi2f(uf.w) + hi2f(ud.w) + bias[c0+7];
  float l = 0.f;
  #pragma unroll
  for (int j = 0; j < 8; ++j) {
    v[j] = v[j] > 0.f ? v[j] : 0.01f * v[j];
    l += v[j] * watt[c0 + j];
  }
  size_t obase = (size_t)(b*OROW + p)*64 + c0;
  if (f32) {
    float4 o0; o0.x = v[0]; o0.y = v[1]; o0.z = v[2]; o0.w = v[3];
    float4 o1; o1.x = v[4]; o1.y = v[5]; o1.z = v[6]; o1.w = v[7];
    *reinterpret_cast<float4*>((float*)out + obase)     = o0;
    *reinterpret_cast<float4*>((float*)out + obase + 4) = o1;
  } else {
    uint4 o;
    o.x = ((u32)f2bu(v[1]) << 16) | f2bu(v[0]);
    o.y = ((u32)f2bu(v[3]) << 16) | f2bu(v[2]);
    o.z = ((u32)f2bu(v[5]) << 16) | f2bu(v[4]);
    o.w = ((u32)f2bu(v[7]) << 16) | f2bu(v[6]);
    *reinterpret_cast<uint4*>((u16*)out + obase) = o;
  }
  l += __shfl_down(l, 4, 8);
  l += __shfl_down(l, 2, 8);
  l += __shfl_down(l, 1, 8);
  if (sub == 0) {
    logits[b*P_ + p] = l;
    ld_log[wave * 8 + grp] = l;
  }
  __syncthreads();
  if (t < 32) {
    float li = ld_log[t];
    float m = li;
    #pragma unroll
    for (int o = 16; o > 0; o >>= 1) m = fmaxf(m, __shfl_xor(m, o, 32));
    float sv = __expf(li - m);
    #pragma unroll
    for (int o = 16; o > 0; o >>= 1) sv += __shfl_xor(sv, o, 32);
    if (t == 0) { mpart[blockIdx.x] = m; spart[blockIdx.x] = sv; }
  }
}

// ---------- Kernel D: h_out ----------
// grid (N_, 4), block 256 = 4 waves (one batch each). Wave merges its batch's
// 500 softmax partials, then 4 edge-groups x 16 ch gather-dot over its node's
// edge range (src sorted -> binary search).
__global__ __launch_bounds__(256) void k_hout(
    const void* __restrict__ x,
    const bf16* __restrict__ h, const float* __restrict__ logits,
    const float* __restrict__ mpart, const float* __restrict__ spart,
    const int* __restrict__ src, const int* __restrict__ dst,
    void* __restrict__ out) {
  const int f32 = detect_f32(x);
  int n = blockIdx.x;
  int t = threadIdx.x;
  int wave = t >> 6, lane = t & 63;
  int b = blockIdx.y * 4 + wave;
  // merge 500 partials -> (m, s)
  float m = -1e30f, s = 0.f;
  for (int j = lane; j < 500; j += 64) {
    float mj = mpart[500*b + j], sj = spart[500*b + j];
    float nm = fmaxf(m, mj);
    s = s * __expf(m - nm) + sj * __expf(mj - nm);
    m = nm;
  }
  #pragma unroll
  for (int o = 32; o > 0; o >>= 1) {
    float mo = __shfl_xor(m, o, 64);
    float so = __shfl_xor(s, o, 64);
    float nm = fmaxf(m, mo);
    s = s * __expf(m - nm) + so * __expf(mo - nm);
    m = nm;
  }
  float inv = 1.0f / s;
  // edge range for node n
  int lo = 0, hi = P_;
  while (lo < hi) { int mid = (lo + hi) >> 1; if (src[mid] < n) lo = mid + 1; else hi = mid; }
  int start = lo;
  hi = P_;
  while (lo < hi) { int mid = (lo + hi) >> 1; if (src[mid] <= n) lo = mid + 1; else hi = mid; }
  int end = lo;
  int grp = lane >> 4, sub = lane & 15, c0 = sub * 4;
  float a0 = 0.f, a1 = 0.f, a2 = 0.f, a3 = 0.f;
  for (int p = start + grp; p < end; p += 4) {
    float a = __expf(logits[b*P_ + p] - m) * inv;
    int dn = dst[p];
    ushort4 hv = *reinterpret_cast<const ushort4*>((const u16*)h + (size_t)(b*N_ + dn)*64 + c0);
    a0 += a * u2f(hv.x); a1 += a * u2f(hv.y);
    a2 += a * u2f(hv.z); a3 += a * u2f(hv.w);
  }
  a0 += __shfl_xor(a0, 16, 64); a0 += __shfl_xor(a0, 32, 64);
  a1 += __shfl_xor(a1, 16, 64); a1 += __shfl_xor(a1, 32, 64);
  a2 += __shfl_xor(a2, 16, 64); a2 += __shfl_xor(a2, 32, 64);
  a3 += __shfl_xor(a3, 16, 64); a3 += __shfl_xor(a3, 32, 64);
  if (grp == 0) {
    size_t obase = (size_t)(b*OROW + P_ + n)*64 + c0;
    if (f32) {
      float4 o4; o4.x = a0; o4.y = a1; o4.z = a2; o4.w = a3;
      *reinterpret_cast<float4*>((float*)out + obase) = o4;
    } else {
      ushort4 o4;
      o4.x = f2bu(a0); o4.y = f2bu(a1); o4.z = f2bu(a2); o4.w = f2bu(a3);
      *reinterpret_cast<ushort4*>((u16*)out + obase) = o4;
    }
  }
}

extern "C" void kernel_launch(void* const* d_in, const int* in_sizes, int n_in,
                              void* d_out, int out_size, void* d_ws, size_t ws_size,
                              hipStream_t stream) {
  const void* x      = d_in[0];
  const void* W_edge = d_in[1];
  const void* W_node = d_in[2];
  const void* b_node = d_in[3];
  const void* W_comb = d_in[4];
  const void* b_comb = d_in[5];
  const void* w_attn = d_in[6];
  const int* src  = (const int*)d_in[7];
  const int* dst  = (const int*)d_in[8];
  const int* eidx = (const int*)d_in[9];

  // workspace layout
  float* A1 = (float*)d_ws;              // 4096
  float* A2 = A1 + 4096;                 // 4096
  float* A3 = A2 + 4096;                 // 4096
  float* c1 = A3 + 4096;                 // 64
  float* c3 = c1 + 64;                   // 64
  float* logits = c3 + 64;               // B*P = 256000
  float* mpart = logits + B_*P_;         // 8000
  float* spart = mpart + 8000;           // 8000
  bf16* h  = (bf16*)(spart + 8000);      // B*N*64
  bf16* hs = h  + B_*N_*64;
  bf16* hd = hs + B_*N_*64;
  bf16* fe = hd + B_*N_*64;              // B*E*64

  k_pre<<<49, 256, 0, stream>>>(x, W_edge, W_node, b_node, W_comb, A1, A2, A3, c1, c3);
  k_transform<<<3000, 256, 0, stream>>>(x, W_node, b_node, A1, A2, A3, c1, c3, h, hs, hd, fe);
  k_combine<<<(B_*P_)/32, 256, 0, stream>>>(x, hs, hd, fe, b_comb, w_attn, src, dst, eidx, d_out, logits, mpart, spart);
  k_hout<<<dim3(N_, B_/4), 256, 0, stream>>>(x, h, logits, mpart, spart, src, dst, d_out);
}

// Round 5
// 196.382 us; speedup vs baseline: 1.5429x; 1.1300x over previous
//
#include <hip/hip_runtime.h>
#include <hip/hip_bf16.h>

#define B_ 16
#define N_ 2000
#define E_ 8000
#define P_ 16000
#define XROW (E_ + N_)   // 10000 rows per batch in x
#define OROW (P_ + N_)   // 18000 rows per batch in out

typedef __hip_bfloat16 bf16;
typedef unsigned short u16;
typedef unsigned int u32;
typedef __attribute__((ext_vector_type(8))) short short8;   // 8 bf16 in 4 VGPRs
typedef __attribute__((ext_vector_type(4))) float f32x4;

__device__ __forceinline__ float b2f(bf16 v) { return __bfloat162float(v); }
__device__ __forceinline__ float u2f(u16 u) { return __uint_as_float(((u32)u) << 16); }
__device__ __forceinline__ float lo2f(u32 u) { return __uint_as_float(u << 16); }
__device__ __forceinline__ float hi2f(u32 u) { return __uint_as_float(u & 0xFFFF0000u); }
__device__ __forceinline__ u16 f2bu(float v) {
  bf16 b = __float2bfloat16(v);
  return *reinterpret_cast<u16*>(&b);
}

// dtype-agnostic input load
__device__ __forceinline__ float ldin(const void* p, int i, int f32) {
  return f32 ? ((const float*)p)[i] : __bfloat162float(((const bf16*)p)[i]);
}

// per-block dtype self-detect (see r2): view first 512B of x as bf16; f32 data
// shows ~70% wild/non-finite values in the low halves.
__device__ __forceinline__ int detect_f32(const void* x) {
  int lane = threadIdx.x & 63;
  ushort4 v = reinterpret_cast<const ushort4*>(x)[lane];
  int bad = 0;
  float f0 = u2f(v.x), f1 = u2f(v.y), f2 = u2f(v.z), f3 = u2f(v.w);
  if (!(fabsf(f0) < 1e4f)) bad++;
  if (!(fabsf(f1) < 1e4f)) bad++;
  if (!(fabsf(f2) < 1e4f)) bad++;
  if (!(fabsf(f3) < 1e4f)) bad++;
  unsigned long long m = __ballot(bad > 0);
  return __popcll(m) > 8;
}

// 4 consecutive input elems -> 4 bf16 (packed ushort4)
__device__ __forceinline__ ushort4 ld4b(const void* p, size_t i, int f32) {
  ushort4 o;
  if (f32) {
    float4 v = *reinterpret_cast<const float4*>((const float*)p + i);
    o.x = f2bu(v.x); o.y = f2bu(v.y); o.z = f2bu(v.z); o.w = f2bu(v.w);
  } else {
    o = *reinterpret_cast<const ushort4*>((const u16*)p + i);
  }
  return o;
}

// ---------- Kernel A: combined weight precompute ----------
// W_comb = [W1; W2; W3]. A1 = W_node@W1, A2 = W_edge@W2, A3 = W_node@W3,
// c1 = b_node@W1, c3 = b_node@W3
__global__ __launch_bounds__(256) void k_pre(
    const void* __restrict__ x,
    const void* __restrict__ W_edge, const void* __restrict__ W_node,
    const void* __restrict__ b_node, const void* __restrict__ W_comb,
    float* __restrict__ A1, float* __restrict__ A2, float* __restrict__ A3,
    float* __restrict__ c1, float* __restrict__ c3) {
  const int f32 = detect_f32(x);
  int o = blockIdx.x * 256 + threadIdx.x;
  if (o < 4096) {
    int i = o >> 6, j = o & 63;
    float a = 0.f;
    for (int k = 0; k < 64; ++k) a += ldin(W_node, i*64+k, f32) * ldin(W_comb, k*64+j, f32);
    A1[o] = a;
  } else if (o < 8192) {
    int oo = o - 4096; int i = oo >> 6, j = oo & 63;
    float a = 0.f;
    for (int k = 0; k < 64; ++k) a += ldin(W_edge, i*64+k, f32) * ldin(W_comb, (64+k)*64+j, f32);
    A2[oo] = a;
  } else if (o < 12288) {
    int oo = o - 8192; int i = oo >> 6, j = oo & 63;
    float a = 0.f;
    for (int k = 0; k < 64; ++k) a += ldin(W_node, i*64+k, f32) * ldin(W_comb, (128+k)*64+j, f32);
    A3[oo] = a;
  } else if (o < 12352) {
    int j = o - 12288;
    float a = 0.f;
    for (int k = 0; k < 64; ++k) a += ldin(b_node, k, f32) * ldin(W_comb, k*64+j, f32);
    c1[j] = a;
  } else if (o < 12416) {
    int j = o - 12352;
    float a = 0.f;
    for (int k = 0; k < 64; ++k) a += ldin(b_node, k, f32) * ldin(W_comb, (128+k)*64+j, f32);
    c3[j] = a;
  }
}

// ---------- Kernel B: fused node+edge transform, MFMA bf16 ----------
// blocks [0,500): node rows, 64/block: [h|hs|hd](64x192) = X(64x64) @ Wn(64x192)
// blocks [500,1500): edge rows, 128/block: fe(128x64) = X(128x64) @ A2(64x64)
// LDS: x-tile bf16 pitch 72 (16B-aligned rows, bank-stride 4 -> <=2-way, free);
//      weights transposed Wt[col][k] bf16 pitch 72.
#define PITCH 72
__global__ __launch_bounds__(256) void k_transform(
    const void* __restrict__ x, const void* __restrict__ W_node,
    const void* __restrict__ b_node,
    const float* __restrict__ A1, const float* __restrict__ A2,
    const float* __restrict__ A3,
    const float* __restrict__ c1, const float* __restrict__ c3,
    bf16* __restrict__ h, bf16* __restrict__ hs, bf16* __restrict__ hd,
    bf16* __restrict__ fe) {
  __shared__ u16 smem[128*PITCH + 64*PITCH < 256*PITCH ? 256*PITCH : 256*PITCH]; // 36864 B
  const int f32 = detect_f32(x);
  int t = threadIdx.x;
  int wave = t >> 6, lane = t & 63;
  int m16 = lane & 15, q = lane >> 4;
  if (blockIdx.x < 500) {
    u16* xs = smem;                 // 64 x PITCH
    u16* Wt = smem + 64*PITCH;      // 192 x PITCH (transposed weights)
    int row0 = blockIdx.x * 64;
    // stage x rows (64x64) as bf16
    for (int i = t*4; i < 4096; i += 1024) {
      int r = i >> 6, k = i & 63;
      int row = row0 + r;
      int b = row / N_, n = row - b * N_;
      *reinterpret_cast<ushort4*>(&xs[r*PITCH + k]) =
          ld4b(x, (size_t)(b * XROW + E_ + n) * 64 + k, f32);
    }
    // stage transposed weights: Wt[c][k], c<64: W_node[k][c]; c<128: A1[k][c-64]; else A3[k][c-128]
    for (int idx = t; idx < 192*16; idx += 256) {
      int c = idx >> 4, kg = (idx & 15) * 4;
      ushort4 o;
      u16* ov = (u16*)&o;
      #pragma unroll
      for (int j = 0; j < 4; ++j) {
        int k = kg + j;
        float v;
        if (c < 64)        v = ldin(W_node, k*64 + c, f32);
        else if (c < 128)  v = A1[k*64 + (c - 64)];
        else               v = A3[k*64 + (c - 128)];
        ov[j] = f2bu(v);
      }
      *reinterpret_cast<ushort4*>(&Wt[c*PITCH + kg]) = o;
    }
    __syncthreads();
    // wave w: row-tile w (16 rows), 12 col-tiles, K=64 (2 mfma each)
    int mrow = wave*16 + m16;
    short8 af0 = *reinterpret_cast<short8*>(&xs[mrow*PITCH + q*8]);
    short8 af1 = *reinterpret_cast<short8*>(&xs[mrow*PITCH + 32 + q*8]);
    f32x4 acc[12];
    #pragma unroll
    for (int c = 0; c < 12; ++c) acc[c] = (f32x4){0.f, 0.f, 0.f, 0.f};
    #pragma unroll
    for (int c = 0; c < 12; ++c) {
      short8 bf0 = *reinterpret_cast<short8*>(&Wt[(c*16 + m16)*PITCH + q*8]);
      short8 bf1 = *reinterpret_cast<short8*>(&Wt[(c*16 + m16)*PITCH + 32 + q*8]);
      acc[c] = __builtin_amdgcn_mfma_f32_16x16x32_bf16(af0, bf0, acc[c], 0, 0, 0);
      acc[c] = __builtin_amdgcn_mfma_f32_16x16x32_bf16(af1, bf1, acc[c], 0, 0, 0);
    }
    // epilogue: D col = lane&15, row = q*4 + reg
    #pragma unroll
    for (int c = 0; c < 12; ++c) {
      int seg = c >> 2;             // 0:h 1:hs 2:hd
      int lcol = (c*16 + m16) & 63;
      float bias = (seg == 0) ? ldin(b_node, lcol, f32) : (seg == 1 ? c1[lcol] : c3[lcol]);
      bf16* tgt = (seg == 0) ? h : (seg == 1 ? hs : hd);
      #pragma unroll
      for (int r = 0; r < 4; ++r) {
        int row = row0 + wave*16 + q*4 + r;
        tgt[(size_t)row*64 + lcol] = __float2bfloat16(acc[c][r] + bias);
      }
    }
  } else {
    u16* xs = smem;                 // 128 x PITCH
    u16* Wt = smem + 128*PITCH;     // 64 x PITCH
    int row0 = (blockIdx.x - 500) * 128;
    for (int i = t*4; i < 8192; i += 1024) {
      int r = i >> 6, k = i & 63;
      int row = row0 + r;
      int b = row / E_, e = row - b * E_;
      *reinterpret_cast<ushort4*>(&xs[r*PITCH + k]) =
          ld4b(x, (size_t)(b * XROW + e) * 64 + k, f32);
    }
    for (int idx = t; idx < 64*16; idx += 256) {
      int c = idx >> 4, kg = (idx & 15) * 4;
      ushort4 o;
      u16* ov = (u16*)&o;
      #pragma unroll
      for (int j = 0; j < 4; ++j) ov[j] = f2bu(A2[(kg + j)*64 + c]);
      *reinterpret_cast<ushort4*>(&Wt[c*PITCH + kg]) = o;
    }
    __syncthreads();
    // wave w: row-tiles 2w, 2w+1 (32 rows), 4 col-tiles
    short8 af[2][2];
    #pragma unroll
    for (int rt = 0; rt < 2; ++rt) {
      int mrow = wave*32 + rt*16 + m16;
      af[rt][0] = *reinterpret_cast<short8*>(&xs[mrow*PITCH + q*8]);
      af[rt][1] = *reinterpret_cast<short8*>(&xs[mrow*PITCH + 32 + q*8]);
    }
    f32x4 acc[2][4];
    #pragma unroll
    for (int rt = 0; rt < 2; ++rt)
      #pragma unroll
      for (int c = 0; c < 4; ++c) acc[rt][c] = (f32x4){0.f, 0.f, 0.f, 0.f};
    #pragma unroll
    for (int c = 0; c < 4; ++c) {
      short8 bf0 = *reinterpret_cast<short8*>(&Wt[(c*16 + m16)*PITCH + q*8]);
      short8 bf1 = *reinterpret_cast<short8*>(&Wt[(c*16 + m16)*PITCH + 32 + q*8]);
      #pragma unroll
      for (int rt = 0; rt < 2; ++rt) {
        acc[rt][c] = __builtin_amdgcn_mfma_f32_16x16x32_bf16(af[rt][0], bf0, acc[rt][c], 0, 0, 0);
        acc[rt][c] = __builtin_amdgcn_mfma_f32_16x16x32_bf16(af[rt][1], bf1, acc[rt][c], 0, 0, 0);
      }
    }
    #pragma unroll
    for (int rt = 0; rt < 2; ++rt)
      #pragma unroll
      for (int c = 0; c < 4; ++c) {
        int col = c*16 + m16;
        #pragma unroll
        for (int r = 0; r < 4; ++r) {
          int row = row0 + wave*32 + rt*16 + q*4 + r;
          fe[(size_t)row*64 + col] = __float2bfloat16(acc[rt][c][r]);
        }
      }
  }
}

// ---------- Kernel C: gather+combine+lrelu+logit + per-block softmax partial --
// 8 lanes/row x 8 ch (uint4 = 16B gathers), 32 rows/block (all same batch).
__global__ __launch_bounds__(256) void k_combine(
    const void* __restrict__ x,
    const bf16* __restrict__ hs, const bf16* __restrict__ hd,
    const bf16* __restrict__ fe, const void* __restrict__ b_comb,
    const void* __restrict__ w_attn,
    const int* __restrict__ src, const int* __restrict__ dst,
    const int* __restrict__ eidx,
    void* __restrict__ out, float* __restrict__ logits,
    float* __restrict__ mpart, float* __restrict__ spart) {
  const int f32 = detect_f32(x);
  __shared__ float bias[64], watt[64];
  __shared__ float ld_log[32];
  int t = threadIdx.x;
  if (t < 64) { bias[t] = ldin(b_comb, t, f32); watt[t] = ldin(w_attn, t, f32); }
  __syncthreads();
  int lane = t & 63, wave = t >> 6;
  int grp = lane >> 3, sub = lane & 7, c0 = sub * 8;
  int r = blockIdx.x * 32 + wave * 8 + grp;   // [0, B*P)
  int b = r / P_, p = r - b * P_;
  int s = src[p], d2 = dst[p], e = eidx[p];
  uint4 ua = *reinterpret_cast<const uint4*>((const u16*)hs + (size_t)(b*N_ + s)*64 + c0);
  uint4 uf = *reinterpret_cast<const uint4*>((const u16*)fe + (size_t)(b*E_ + e)*64 + c0);
  uint4 ud = *reinterpret_cast<const uint4*>((const u16*)hd + (size_t)(b*N_ + d2)*64 + c0);
  float v[8];
  v[0] = lo2f(ua.x) + lo2f(uf.x) + lo2f(ud.x) + bias[c0+0];
  v[1] = hi2f(ua.x) + hi2f(uf.x) + hi2f(ud.x) + bias[c0+1];
  v[2] = lo2f(ua.y) + lo2f(uf.y) + lo2f(ud.y) + bias[c0+2];
  v[3] = hi2f(ua.y) + hi2f(uf.y) + hi2f(ud.y) + bias[c0+3];
  v[4] = lo2f(ua.z) + lo2f(uf.z) + lo2f(ud.z) + bias[c0+4];
  v[5] = hi2f(ua.z) + hi2f(uf.z) + hi2f(ud.z) + bias[c0+5];
  v[6] = lo2f(ua.w) + lo2f(uf.w) + lo2f(ud.w) + bias[c0+6];
  v[7] = hi2f(ua.w) + hi2f(uf.w) + hi2f(ud.w) + bias[c0+7];
  float l = 0.f;
  #pragma unroll
  for (int j = 0; j < 8; ++j) {
    v[j] = v[j] > 0.f ? v[j] : 0.01f * v[j];
    l += v[j] * watt[c0 + j];
  }
  size_t obase = (size_t)(b*OROW + p)*64 + c0;
  if (f32) {
    float4 o0; o0.x = v[0]; o0.y = v[1]; o0.z = v[2]; o0.w = v[3];
    float4 o1; o1.x = v[4]; o1.y = v[5]; o1.z = v[6]; o1.w = v[7];
    *reinterpret_cast<float4*>((float*)out + obase)     = o0;
    *reinterpret_cast<float4*>((float*)out + obase + 4) = o1;
  } else {
    uint4 o;
    o.x = ((u32)f2bu(v[1]) << 16) | f2bu(v[0]);
    o.y = ((u32)f2bu(v[3]) << 16) | f2bu(v[2]);
    o.z = ((u32)f2bu(v[5]) << 16) | f2bu(v[4]);
    o.w = ((u32)f2bu(v[7]) << 16) | f2bu(v[6]);
    *reinterpret_cast<uint4*>((u16*)out + obase) = o;
  }
  l += __shfl_down(l, 4, 8);
  l += __shfl_down(l, 2, 8);
  l += __shfl_down(l, 1, 8);
  if (sub == 0) {
    logits[b*P_ + p] = l;
    ld_log[wave * 8 + grp] = l;
  }
  __syncthreads();
  if (t < 32) {
    float li = ld_log[t];
    float m = li;
    #pragma unroll
    for (int o = 16; o > 0; o >>= 1) m = fmaxf(m, __shfl_xor(m, o, 32));
    float sv = __expf(li - m);
    #pragma unroll
    for (int o = 16; o > 0; o >>= 1) sv += __shfl_xor(sv, o, 32);
    if (t == 0) { mpart[blockIdx.x] = m; spart[blockIdx.x] = sv; }
  }
}

// ---------- Kernel D: h_out ----------
// grid (N_, 4), block 256 = 4 waves (one batch each). Wave merges its batch's
// 500 softmax partials, then 4 edge-groups x 16 ch gather-dot over its node's
// edge range (src sorted -> binary search).
__global__ __launch_bounds__(256) void k_hout(
    const void* __restrict__ x,
    const bf16* __restrict__ h, const float* __restrict__ logits,
    const float* __restrict__ mpart, const float* __restrict__ spart,
    const int* __restrict__ src, const int* __restrict__ dst,
    void* __restrict__ out) {
  const int f32 = detect_f32(x);
  int n = blockIdx.x;
  int t = threadIdx.x;
  int wave = t >> 6, lane = t & 63;
  int b = blockIdx.y * 4 + wave;
  // merge 500 partials -> (m, s)
  float m = -1e30f, s = 0.f;
  for (int j = lane; j < 500; j += 64) {
    float mj = mpart[500*b + j], sj = spart[500*b + j];
    float nm = fmaxf(m, mj);
    s = s * __expf(m - nm) + sj * __expf(mj - nm);
    m = nm;
  }
  #pragma unroll
  for (int o = 32; o > 0; o >>= 1) {
    float mo = __shfl_xor(m, o, 64);
    float so = __shfl_xor(s, o, 64);
    float nm = fmaxf(m, mo);
    s = s * __expf(m - nm) + so * __expf(mo - nm);
    m = nm;
  }
  float inv = 1.0f / s;
  // edge range for node n
  int lo = 0, hi = P_;
  while (lo < hi) { int mid = (lo + hi) >> 1; if (src[mid] < n) lo = mid + 1; else hi = mid; }
  int start = lo;
  hi = P_;
  while (lo < hi) { int mid = (lo + hi) >> 1; if (src[mid] <= n) lo = mid + 1; else hi = mid; }
  int end = lo;
  int grp = lane >> 4, sub = lane & 15, c0 = sub * 4;
  float a0 = 0.f, a1 = 0.f, a2 = 0.f, a3 = 0.f;
  for (int p = start + grp; p < end; p += 4) {
    float a = __expf(logits[b*P_ + p] - m) * inv;
    int dn = dst[p];
    ushort4 hv = *reinterpret_cast<const ushort4*>((const u16*)h + (size_t)(b*N_ + dn)*64 + c0);
    a0 += a * u2f(hv.x); a1 += a * u2f(hv.y);
    a2 += a * u2f(hv.z); a3 += a * u2f(hv.w);
  }
  a0 += __shfl_xor(a0, 16, 64); a0 += __shfl_xor(a0, 32, 64);
  a1 += __shfl_xor(a1, 16, 64); a1 += __shfl_xor(a1, 32, 64);
  a2 += __shfl_xor(a2, 16, 64); a2 += __shfl_xor(a2, 32, 64);
  a3 += __shfl_xor(a3, 16, 64); a3 += __shfl_xor(a3, 32, 64);
  if (grp == 0) {
    size_t obase = (size_t)(b*OROW + P_ + n)*64 + c0;
    if (f32) {
      float4 o4; o4.x = a0; o4.y = a1; o4.z = a2; o4.w = a3;
      *reinterpret_cast<float4*>((float*)out + obase) = o4;
    } else {
      ushort4 o4;
      o4.x = f2bu(a0); o4.y = f2bu(a1); o4.z = f2bu(a2); o4.w = f2bu(a3);
      *reinterpret_cast<ushort4*>((u16*)out + obase) = o4;
    }
  }
}

extern "C" void kernel_launch(void* const* d_in, const int* in_sizes, int n_in,
                              void* d_out, int out_size, void* d_ws, size_t ws_size,
                              hipStream_t stream) {
  const void* x      = d_in[0];
  const void* W_edge = d_in[1];
  const void* W_node = d_in[2];
  const void* b_node = d_in[3];
  const void* W_comb = d_in[4];
  const void* b_comb = d_in[5];
  const void* w_attn = d_in[6];
  const int* src  = (const int*)d_in[7];
  const int* dst  = (const int*)d_in[8];
  const int* eidx = (const int*)d_in[9];

  // workspace layout
  float* A1 = (float*)d_ws;              // 4096
  float* A2 = A1 + 4096;                 // 4096
  float* A3 = A2 + 4096;                 // 4096
  float* c1 = A3 + 4096;                 // 64
  float* c3 = c1 + 64;                   // 64
  float* logits = c3 + 64;               // B*P = 256000
  float* mpart = logits + B_*P_;         // 8000
  float* spart = mpart + 8000;           // 8000
  bf16* h  = (bf16*)(spart + 8000);      // B*N*64
  bf16* hs = h  + B_*N_*64;
  bf16* hd = hs + B_*N_*64;
  bf16* fe = hd + B_*N_*64;              // B*E*64

  k_pre<<<49, 256, 0, stream>>>(x, W_edge, W_node, b_node, W_comb, A1, A2, A3, c1, c3);
  k_transform<<<1500, 256, 0, stream>>>(x, W_node, b_node, A1, A2, A3, c1, c3, h, hs, hd, fe);
  k_combine<<<(B_*P_)/32, 256, 0, stream>>>(x, hs, hd, fe, b_comb, w_attn, src, dst, eidx, d_out, logits, mpart, spart);
  k_hout<<<dim3(N_, B_/4), 256, 0, stream>>>(x, h, logits, mpart, spart, src, dst, d_out);
}

// Round 6
// 179.790 us; speedup vs baseline: 1.6853x; 1.0923x over previous
//
#include <hip/hip_runtime.h>
#include <hip/hip_bf16.h>

#define B_ 16
#define N_ 2000
#define E_ 8000
#define P_ 16000
#define XROW (E_ + N_)   // 10000 rows per batch in x
#define OROW (P_ + N_)   // 18000 rows per batch in out

typedef __hip_bfloat16 bf16;
typedef unsigned short u16;
typedef unsigned int u32;
typedef __attribute__((ext_vector_type(8))) short short8;   // 8 bf16 in 4 VGPRs
typedef __attribute__((ext_vector_type(4))) float f32x4;

__device__ __forceinline__ float b2f(bf16 v) { return __bfloat162float(v); }
__device__ __forceinline__ float u2f(u16 u) { return __uint_as_float(((u32)u) << 16); }
__device__ __forceinline__ float lo2f(u32 u) { return __uint_as_float(u << 16); }
__device__ __forceinline__ float hi2f(u32 u) { return __uint_as_float(u & 0xFFFF0000u); }
__device__ __forceinline__ u16 f2bu(float v) {
  bf16 b = __float2bfloat16(v);
  return *reinterpret_cast<u16*>(&b);
}

// dtype-agnostic input load
__device__ __forceinline__ float ldin(const void* p, int i, int f32) {
  return f32 ? ((const float*)p)[i] : __bfloat162float(((const bf16*)p)[i]);
}

// per-block dtype self-detect (see r2): view first 512B of x as bf16; f32 data
// shows ~70% wild/non-finite values in the low halves.
__device__ __forceinline__ int detect_f32(const void* x) {
  int lane = threadIdx.x & 63;
  ushort4 v = reinterpret_cast<const ushort4*>(x)[lane];
  int bad = 0;
  float f0 = u2f(v.x), f1 = u2f(v.y), f2 = u2f(v.z), f3 = u2f(v.w);
  if (!(fabsf(f0) < 1e4f)) bad++;
  if (!(fabsf(f1) < 1e4f)) bad++;
  if (!(fabsf(f2) < 1e4f)) bad++;
  if (!(fabsf(f3) < 1e4f)) bad++;
  unsigned long long m = __ballot(bad > 0);
  return __popcll(m) > 8;
}

// 8 consecutive input elems -> short8 of bf16 (A-fragment load)
__device__ __forceinline__ short8 ld8b(const void* p, size_t i, int f32) {
  short8 r;
  if (f32) {
    const float* f = (const float*)p + i;
    float4 v0 = *reinterpret_cast<const float4*>(f);
    float4 v1 = *reinterpret_cast<const float4*>(f + 4);
    u16* o = (u16*)&r;
    o[0] = f2bu(v0.x); o[1] = f2bu(v0.y); o[2] = f2bu(v0.z); o[3] = f2bu(v0.w);
    o[4] = f2bu(v1.x); o[5] = f2bu(v1.y); o[6] = f2bu(v1.z); o[7] = f2bu(v1.w);
  } else {
    r = *reinterpret_cast<const short8*>((const u16*)p + i);
  }
  return r;
}

// ---------- Kernel A: weight precompute (transposed bf16) + rowptr ----------
// Wtn[c][k] (192x64): c<64 -> W_node^T; c<128 -> (W_node@W1)^T; else (W_node@W3)^T
// Wte[c][k] (64x64): (W_edge@W2)^T.  c1 = b_node@W1, c3 = b_node@W3.
// rowptr[n] = lower_bound(src, n), n in [0,2000].
__global__ __launch_bounds__(256) void k_pre(
    const void* __restrict__ x,
    const void* __restrict__ W_edge, const void* __restrict__ W_node,
    const void* __restrict__ b_node, const void* __restrict__ W_comb,
    const int* __restrict__ src,
    u16* __restrict__ Wtn, u16* __restrict__ Wte,
    float* __restrict__ c1, float* __restrict__ c3,
    int* __restrict__ rowptr) {
  const int f32 = detect_f32(x);
  int o = blockIdx.x * 256 + threadIdx.x;
  if (o < 4096) {
    int c = o >> 6, k = o & 63;
    Wtn[c*64 + k] = f2bu(ldin(W_node, k*64 + c, f32));
  } else if (o < 12288) {
    int oo = o - 4096;            // [0, 8192)
    int cc = oo >> 6, k = oo & 63;
    int col = cc & 63;
    int base = (cc < 64) ? 0 : 128;
    float a = 0.f;
    for (int j = 0; j < 64; ++j)
      a += ldin(W_node, k*64 + j, f32) * ldin(W_comb, (base + j)*64 + col, f32);
    Wtn[(64 + cc)*64 + k] = f2bu(a);
  } else if (o < 16384) {
    int oo = o - 12288;
    int c = oo >> 6, k = oo & 63;
    float a = 0.f;
    for (int j = 0; j < 64; ++j)
      a += ldin(W_edge, k*64 + j, f32) * ldin(W_comb, (64 + j)*64 + c, f32);
    Wte[c*64 + k] = f2bu(a);
  } else if (o < 16448) {
    int j = o - 16384;
    float a = 0.f;
    for (int k = 0; k < 64; ++k) a += ldin(b_node, k, f32) * ldin(W_comb, k*64 + j, f32);
    c1[j] = a;
  } else if (o < 16512) {
    int j = o - 16448;
    float a = 0.f;
    for (int k = 0; k < 64; ++k) a += ldin(b_node, k, f32) * ldin(W_comb, (128 + k)*64 + j, f32);
    c3[j] = a;
  } else if (o < 16512 + N_ + 1) {
    int n = o - 16512;
    int lo = 0, hi = P_;
    while (lo < hi) { int mid = (lo + hi) >> 1; if (src[mid] < n) lo = mid + 1; else hi = mid; }
    rowptr[n] = lo;
  }
}

// ---------- Kernel B: fused node+edge transform, MFMA, LDS-free ----------
// blocks [0,500): node rows, 64/block (4 waves x 16 rows), 12 col-tiles:
//   [h|hs|hd](64x192) = X @ Wn(64x192)
// blocks [500,1500): edge rows, 128/block (4 waves x 32 rows), 4 col-tiles:
//   fe(128x64) = X @ A2
// A-frags straight from global x (coalesced: lanes {m,m+16,m+32,m+48} cover one
// row's 128B half); B-frags from precomputed transposed weights (L1-resident).
__global__ __launch_bounds__(256) void k_transform(
    const void* __restrict__ x,
    const u16* __restrict__ Wtn, const u16* __restrict__ Wte,
    const void* __restrict__ b_node,
    const float* __restrict__ c1, const float* __restrict__ c3,
    bf16* __restrict__ h, bf16* __restrict__ hs, bf16* __restrict__ hd,
    bf16* __restrict__ fe) {
  const int f32 = detect_f32(x);
  int t = threadIdx.x;
  int wave = t >> 6, lane = t & 63;
  int m16 = lane & 15, q = lane >> 4;
  if (blockIdx.x < 500) {
    int row0 = blockIdx.x * 64 + wave * 16;
    int arow = row0 + m16;
    int b = arow / N_, n = arow - b * N_;
    size_t xbase = (size_t)(b * XROW + E_ + n) * 64;
    short8 af0 = ld8b(x, xbase + q*8, f32);
    short8 af1 = ld8b(x, xbase + 32 + q*8, f32);
    f32x4 acc[12];
    #pragma unroll
    for (int c = 0; c < 12; ++c) acc[c] = (f32x4){0.f, 0.f, 0.f, 0.f};
    #pragma unroll
    for (int c = 0; c < 12; ++c) {
      short8 b0 = *reinterpret_cast<const short8*>(&Wtn[(c*16 + m16)*64 + q*8]);
      short8 b1 = *reinterpret_cast<const short8*>(&Wtn[(c*16 + m16)*64 + 32 + q*8]);
      acc[c] = __builtin_amdgcn_mfma_f32_16x16x32_bf16(af0, b0, acc[c], 0, 0, 0);
      acc[c] = __builtin_amdgcn_mfma_f32_16x16x32_bf16(af1, b1, acc[c], 0, 0, 0);
    }
    // D: col = m16 (within tile), row = q*4 + r
    #pragma unroll
    for (int c = 0; c < 12; ++c) {
      int seg = c >> 2;             // 0:h 1:hs 2:hd
      int lcol = (c*16 + m16) & 63;
      float bias = (seg == 0) ? ldin(b_node, lcol, f32) : (seg == 1 ? c1[lcol] : c3[lcol]);
      bf16* tgt = (seg == 0) ? h : (seg == 1 ? hs : hd);
      #pragma unroll
      for (int r = 0; r < 4; ++r) {
        int row = row0 + q*4 + r;
        tgt[(size_t)row*64 + lcol] = __float2bfloat16(acc[c][r] + bias);
      }
    }
  } else {
    int row0 = (blockIdx.x - 500) * 128 + wave * 32;
    short8 af[2][2];
    #pragma unroll
    for (int rt = 0; rt < 2; ++rt) {
      int arow = row0 + rt*16 + m16;
      int b = arow / E_, e = arow - b * E_;
      size_t xbase = (size_t)(b * XROW + e) * 64;
      af[rt][0] = ld8b(x, xbase + q*8, f32);
      af[rt][1] = ld8b(x, xbase + 32 + q*8, f32);
    }
    f32x4 acc[2][4];
    #pragma unroll
    for (int rt = 0; rt < 2; ++rt)
      #pragma unroll
      for (int c = 0; c < 4; ++c) acc[rt][c] = (f32x4){0.f, 0.f, 0.f, 0.f};
    #pragma unroll
    for (int c = 0; c < 4; ++c) {
      short8 b0 = *reinterpret_cast<const short8*>(&Wte[(c*16 + m16)*64 + q*8]);
      short8 b1 = *reinterpret_cast<const short8*>(&Wte[(c*16 + m16)*64 + 32 + q*8]);
      #pragma unroll
      for (int rt = 0; rt < 2; ++rt) {
        acc[rt][c] = __builtin_amdgcn_mfma_f32_16x16x32_bf16(af[rt][0], b0, acc[rt][c], 0, 0, 0);
        acc[rt][c] = __builtin_amdgcn_mfma_f32_16x16x32_bf16(af[rt][1], b1, acc[rt][c], 0, 0, 0);
      }
    }
    #pragma unroll
    for (int rt = 0; rt < 2; ++rt)
      #pragma unroll
      for (int c = 0; c < 4; ++c) {
        int col = c*16 + m16;
        #pragma unroll
        for (int r = 0; r < 4; ++r) {
          int row = row0 + rt*16 + q*4 + r;
          fe[(size_t)row*64 + col] = __float2bfloat16(acc[rt][c][r]);
        }
      }
  }
}

// ---------- Kernel C: gather+combine+lrelu+logit + per-block softmax partial --
// 8 lanes/row x 8 ch (uint4 = 16B gathers), 32 rows/block (all same batch).
__global__ __launch_bounds__(256) void k_combine(
    const void* __restrict__ x,
    const bf16* __restrict__ hs, const bf16* __restrict__ hd,
    const bf16* __restrict__ fe, const void* __restrict__ b_comb,
    const void* __restrict__ w_attn,
    const int* __restrict__ src, const int* __restrict__ dst,
    const int* __restrict__ eidx,
    void* __restrict__ out, float* __restrict__ logits,
    float* __restrict__ mpart, float* __restrict__ spart) {
  const int f32 = detect_f32(x);
  __shared__ float bias[64], watt[64];
  __shared__ float ld_log[32];
  int t = threadIdx.x;
  if (t < 64) { bias[t] = ldin(b_comb, t, f32); watt[t] = ldin(w_attn, t, f32); }
  __syncthreads();
  int lane = t & 63, wave = t >> 6;
  int grp = lane >> 3, sub = lane & 7, c0 = sub * 8;
  int r = blockIdx.x * 32 + wave * 8 + grp;   // [0, B*P)
  int b = r / P_, p = r - b * P_;
  int s = src[p], d2 = dst[p], e = eidx[p];
  uint4 ua = *reinterpret_cast<const uint4*>((const u16*)hs + (size_t)(b*N_ + s)*64 + c0);
  uint4 uf = *reinterpret_cast<const uint4*>((const u16*)fe + (size_t)(b*E_ + e)*64 + c0);
  uint4 ud = *reinterpret_cast<const uint4*>((const u16*)hd + (size_t)(b*N_ + d2)*64 + c0);
  float v[8];
  v[0] = lo2f(ua.x) + lo2f(uf.x) + lo2f(ud.x) + bias[c0+0];
  v[1] = hi2f(ua.x) + hi2f(uf.x) + hi2f(ud.x) + bias[c0+1];
  v[2] = lo2f(ua.y) + lo2f(uf.y) + lo2f(ud.y) + bias[c0+2];
  v[3] = hi2f(ua.y) + hi2f(uf.y) + hi2f(ud.y) + bias[c0+3];
  v[4] = lo2f(ua.z) + lo2f(uf.z) + lo2f(ud.z) + bias[c0+4];
  v[5] = hi2f(ua.z) + hi2f(uf.z) + hi2f(ud.z) + bias[c0+5];
  v[6] = lo2f(ua.w) + lo2f(uf.w) + lo2f(ud.w) + bias[c0+6];
  v[7] = hi2f(ua.w) + hi2f(uf.w) + hi2f(ud.w) + bias[c0+7];
  float l = 0.f;
  #pragma unroll
  for (int j = 0; j < 8; ++j) {
    v[j] = v[j] > 0.f ? v[j] : 0.01f * v[j];
    l += v[j] * watt[c0 + j];
  }
  size_t obase = (size_t)(b*OROW + p)*64 + c0;
  if (f32) {
    float4 o0; o0.x = v[0]; o0.y = v[1]; o0.z = v[2]; o0.w = v[3];
    float4 o1; o1.x = v[4]; o1.y = v[5]; o1.z = v[6]; o1.w = v[7];
    *reinterpret_cast<float4*>((float*)out + obase)     = o0;
    *reinterpret_cast<float4*>((float*)out + obase + 4) = o1;
  } else {
    uint4 o;
    o.x = ((u32)f2bu(v[1]) << 16) | f2bu(v[0]);
    o.y = ((u32)f2bu(v[3]) << 16) | f2bu(v[2]);
    o.z = ((u32)f2bu(v[5]) << 16) | f2bu(v[4]);
    o.w = ((u32)f2bu(v[7]) << 16) | f2bu(v[6]);
    *reinterpret_cast<uint4*>((u16*)out + obase) = o;
  }
  l += __shfl_down(l, 4, 8);
  l += __shfl_down(l, 2, 8);
  l += __shfl_down(l, 1, 8);
  if (sub == 0) {
    logits[b*P_ + p] = l;
    ld_log[wave * 8 + grp] = l;
  }
  __syncthreads();
  if (t < 32) {
    float li = ld_log[t];
    float m = li;
    #pragma unroll
    for (int o = 16; o > 0; o >>= 1) m = fmaxf(m, __shfl_xor(m, o, 32));
    float sv = __expf(li - m);
    #pragma unroll
    for (int o = 16; o > 0; o >>= 1) sv += __shfl_xor(sv, o, 32);
    if (t == 0) { mpart[blockIdx.x] = m; spart[blockIdx.x] = sv; }
  }
}

// ---------- Kernel C2: merge 500 partials per batch -> (M, 1/S) ----------
__global__ __launch_bounds__(256) void k_smerge(
    const float* __restrict__ mpart, const float* __restrict__ spart,
    float* __restrict__ mb, float* __restrict__ sb) {
  __shared__ float rm[256], rs[256];
  int b = blockIdx.x, t = threadIdx.x;
  float m = -1e30f, s = 0.f;
  for (int j = t; j < 500; j += 256) {
    float mj = mpart[500*b + j], sj = spart[500*b + j];
    float nm = fmaxf(m, mj);
    s = s * __expf(m - nm) + sj * __expf(mj - nm);
    m = nm;
  }
  rm[t] = m; rs[t] = s; __syncthreads();
  for (int st = 128; st > 0; st >>= 1) {
    if (t < st) {
      float mo = rm[t + st], so = rs[t + st];
      float nm = fmaxf(rm[t], mo);
      rs[t] = rs[t] * __expf(rm[t] - nm) + so * __expf(mo - nm);
      rm[t] = nm;
    }
    __syncthreads();
  }
  if (t == 0) { mb[b] = rm[0]; sb[b] = 1.0f / rs[0]; }
}

// ---------- Kernel D: h_out ----------
// grid (N_, 4), block 256 = 4 waves (one batch each). rowptr gives the node's
// edge range; 4 edge-groups x 16 ch gather-dot; xor-reduce across groups.
__global__ __launch_bounds__(256) void k_hout(
    const void* __restrict__ x,
    const bf16* __restrict__ h, const float* __restrict__ logits,
    const float* __restrict__ mb, const float* __restrict__ sb,
    const int* __restrict__ rowptr, const int* __restrict__ dst,
    void* __restrict__ out) {
  const int f32 = detect_f32(x);
  int n = blockIdx.x;
  int t = threadIdx.x;
  int wave = t >> 6, lane = t & 63;
  int b = blockIdx.y * 4 + wave;
  float m = mb[b], inv = sb[b];
  int start = rowptr[n], end = rowptr[n + 1];
  int grp = lane >> 4, sub = lane & 15, c0 = sub * 4;
  float a0 = 0.f, a1 = 0.f, a2 = 0.f, a3 = 0.f;
  for (int p = start + grp; p < end; p += 4) {
    float a = __expf(logits[b*P_ + p] - m) * inv;
    int dn = dst[p];
    ushort4 hv = *reinterpret_cast<const ushort4*>((const u16*)h + (size_t)(b*N_ + dn)*64 + c0);
    a0 += a * u2f(hv.x); a1 += a * u2f(hv.y);
    a2 += a * u2f(hv.z); a3 += a * u2f(hv.w);
  }
  a0 += __shfl_xor(a0, 16, 64); a0 += __shfl_xor(a0, 32, 64);
  a1 += __shfl_xor(a1, 16, 64); a1 += __shfl_xor(a1, 32, 64);
  a2 += __shfl_xor(a2, 16, 64); a2 += __shfl_xor(a2, 32, 64);
  a3 += __shfl_xor(a3, 16, 64); a3 += __shfl_xor(a3, 32, 64);
  if (grp == 0) {
    size_t obase = (size_t)(b*OROW + P_ + n)*64 + c0;
    if (f32) {
      float4 o4; o4.x = a0; o4.y = a1; o4.z = a2; o4.w = a3;
      *reinterpret_cast<float4*>((float*)out + obase) = o4;
    } else {
      ushort4 o4;
      o4.x = f2bu(a0); o4.y = f2bu(a1); o4.z = f2bu(a2); o4.w = f2bu(a3);
      *reinterpret_cast<ushort4*>((u16*)out + obase) = o4;
    }
  }
}

extern "C" void kernel_launch(void* const* d_in, const int* in_sizes, int n_in,
                              void* d_out, int out_size, void* d_ws, size_t ws_size,
                              hipStream_t stream) {
  const void* x      = d_in[0];
  const void* W_edge = d_in[1];
  const void* W_node = d_in[2];
  const void* b_node = d_in[3];
  const void* W_comb = d_in[4];
  const void* b_comb = d_in[5];
  const void* w_attn = d_in[6];
  const int* src  = (const int*)d_in[7];
  const int* dst  = (const int*)d_in[8];
  const int* eidx = (const int*)d_in[9];

  // workspace layout (f32 units)
  float* logits = (float*)d_ws;          // 256000
  float* mpart  = logits + B_*P_;        // 8000
  float* spart  = mpart + 8000;          // 8000
  float* mb     = spart + 8000;          // 16
  float* sb     = mb + B_;               // 16
  float* c1     = sb + B_;               // 64
  float* c3     = c1 + 64;               // 64
  int*   rowptr = (int*)(c3 + 64);       // 2016 (padded)
  u16*   Wtn    = (u16*)(rowptr + 2016); // 192*64
  u16*   Wte    = Wtn + 192*64;          // 64*64
  bf16*  h      = (bf16*)(Wte + 64*64);  // B*N*64
  bf16*  hs     = h  + B_*N_*64;
  bf16*  hd     = hs + B_*N_*64;
  bf16*  fe     = hd + B_*N_*64;         // B*E*64

  k_pre<<<73, 256, 0, stream>>>(x, W_edge, W_node, b_node, W_comb, src, Wtn, Wte, c1, c3, rowptr);
  k_transform<<<1500, 256, 0, stream>>>(x, Wtn, Wte, b_node, c1, c3, h, hs, hd, fe);
  k_combine<<<(B_*P_)/32, 256, 0, stream>>>(x, hs, hd, fe, b_comb, w_attn, src, dst, eidx, d_out, logits, mpart, spart);
  k_smerge<<<B_, 256, 0, stream>>>(mpart, spart, mb, sb);
  k_hout<<<dim3(N_, B_/4), 256, 0, stream>>>(x, h, logits, mb, sb, rowptr, dst, d_out);
}